// Round 10
// baseline (149.071 us; speedup 1.0000x reference)
//
#include <hip/hip_runtime.h>

#define N_NODES 50000
#define N_EDGES 800000
#define D_INF 64
#define D_HIDF 128
#define NCHAIN 4

typedef __attribute__((ext_vector_type(8))) short bf16x8v;  // 8 bf16 = 4 VGPRs
typedef __attribute__((ext_vector_type(4))) float f32x4;

__device__ __forceinline__ ushort f2bf(float f) {
    unsigned int u = __builtin_bit_cast(unsigned int, f);
    u += 0x7FFF + ((u >> 16) & 1);  // RNE
    return (ushort)(u >> 16);
}

// ---------------------------------------------------------------------------
// Chained adjacency build: head[k][n] = latest edge id with dst n, lane k;
// next[e] = previous edge in that chain. next writes are COALESCED.
// ---------------------------------------------------------------------------

__global__ void init_head_kernel(int* __restrict__ head) {
    int i = blockIdx.x * blockDim.x + threadIdx.x;
    if (i < NCHAIN * N_NODES) head[i] = -1;
}

__global__ void build_chain_kernel(const int* __restrict__ dst,
                                   int* __restrict__ head,
                                   int* __restrict__ next) {
    int e = blockIdx.x * blockDim.x + threadIdx.x;
    if (e < N_EDGES) {
        int t = dst[e];
        int k = e & (NCHAIN - 1);
        int old = atomicExch(&head[k * N_NODES + t], e);
        next[e] = old;
    }
}

// One wave per node; lane = feature. Walk 4 chains concurrently (4-way ILP
// on the dependent next[] loads). agg = x + sum_{neighbors} x[src], bf16 out.
__global__ void __launch_bounds__(256) gather_chain_kernel(
    const float* __restrict__ x, const int* __restrict__ src,
    const int* __restrict__ head, const int* __restrict__ next,
    ushort* __restrict__ aggb)
{
    int wid = (blockIdx.x * blockDim.x + threadIdx.x) >> 6;
    int lane = threadIdx.x & 63;
    if (wid >= N_NODES) return;

    float s0 = x[(size_t)wid * D_INF + lane];
    float s1 = 0.f, s2 = 0.f, s3 = 0.f;

    int e0 = head[0 * N_NODES + wid];
    int e1 = head[1 * N_NODES + wid];
    int e2 = head[2 * N_NODES + wid];
    int e3 = head[3 * N_NODES + wid];

    while (e0 >= 0 || e1 >= 0 || e2 >= 0 || e3 >= 0) {
        int sv0 = 0, sv1 = 0, sv2 = 0, sv3 = 0;
        int n0 = e0, n1 = e1, n2 = e2, n3 = e3;
        bool a0 = e0 >= 0, a1 = e1 >= 0, a2 = e2 >= 0, a3 = e3 >= 0;
        if (a0) { sv0 = src[e0]; n0 = next[e0]; }
        if (a1) { sv1 = src[e1]; n1 = next[e1]; }
        if (a2) { sv2 = src[e2]; n2 = next[e2]; }
        if (a3) { sv3 = src[e3]; n3 = next[e3]; }
        if (a0) s0 += x[(size_t)sv0 * D_INF + lane];
        if (a1) s1 += x[(size_t)sv1 * D_INF + lane];
        if (a2) s2 += x[(size_t)sv2 * D_INF + lane];
        if (a3) s3 += x[(size_t)sv3 * D_INF + lane];
        e0 = n0; e1 = n1; e2 = n2; e3 = n3;
    }
    aggb[(size_t)wid * D_INF + lane] = f2bf((s0 + s1) + (s2 + s3));
}

// ---------------------------------------------------------------------------
// Weight prep: bf16 transposed copies. w1tb[j][l] = W1[l][j]; w2tb[d][j] = W2[j][d]
// ---------------------------------------------------------------------------

__global__ void prep_weights_kernel(const float* __restrict__ W1,
                                    const float* __restrict__ W2,
                                    ushort* __restrict__ w1tb,
                                    ushort* __restrict__ w2tb) {
    int i = blockIdx.x * blockDim.x + threadIdx.x;
    if (i < D_INF * D_HIDF) {
        int j = i >> 6, l = i & 63;
        w1tb[i] = f2bf(W1[l * D_HIDF + j]);
        int d = i >> 7, jj = i & 127;
        w2tb[i] = f2bf(W2[jj * D_INF + d]);
    }
}

// ---------------------------------------------------------------------------
// MLP (MFMA): 64-node tile, 256 threads = 4 waves. Wave w owns node rows
// [16w,16w+16) for BOTH GEMMs -> H is wave-private, no inter-GEMM barrier.
// ---------------------------------------------------------------------------

#define AT_LD 72
#define W1_LD 72
#define HT_LD 136
#define W2_LD 136

__global__ void __launch_bounds__(256) mlp_mfma_kernel(
    const ushort* __restrict__ aggb, const ushort* __restrict__ w1tb,
    const float* __restrict__ b1v, const ushort* __restrict__ w2tb,
    const float* __restrict__ b2v, float* __restrict__ out)
{
    __shared__ __align__(16) ushort atile[64 * AT_LD];
    __shared__ __align__(16) ushort w1s[128 * W1_LD];
    __shared__ __align__(16) ushort w2s[64 * W2_LD];
    __shared__ __align__(16) ushort htile[64 * HT_LD];

    int tid = threadIdx.x;
    int lane = tid & 63;
    int wv = tid >> 6;
    int nb = blockIdx.x * 64;

#pragma unroll
    for (int c = 0; c < 2; c++) {
        int chunk = tid + c * 256;
        int row = chunk >> 3;
        int col = (chunk & 7) * 8;
        ulonglong2 v;
        v.x = 0; v.y = 0;
        if (nb + row < N_NODES)
            v = *reinterpret_cast<const ulonglong2*>(aggb + (size_t)(nb + row) * D_INF + col);
        *reinterpret_cast<ulonglong2*>(&atile[row * AT_LD + col]) = v;
    }
#pragma unroll
    for (int c = 0; c < 4; c++) {
        int chunk = tid + c * 256;
        int row = chunk >> 3;
        int col = (chunk & 7) * 8;
        *reinterpret_cast<ulonglong2*>(&w1s[row * W1_LD + col]) =
            *reinterpret_cast<const ulonglong2*>(w1tb + row * 64 + col);
    }
#pragma unroll
    for (int c = 0; c < 4; c++) {
        int chunk = tid + c * 256;
        int row = chunk >> 4;
        int col = (chunk & 15) * 8;
        *reinterpret_cast<ulonglong2*>(&w2s[row * W2_LD + col]) =
            *reinterpret_cast<const ulonglong2*>(w2tb + row * 128 + col);
    }
    __syncthreads();

    int q = lane >> 4;
    int m = lane & 15;
    int arow = wv * 16 + m;
    int hrow0 = wv * 16 + q * 4;

    // GEMM1: H = A @ W1
    bf16x8v a0 = *reinterpret_cast<const bf16x8v*>(&atile[arow * AT_LD + q * 8]);
    bf16x8v a1 = *reinterpret_cast<const bf16x8v*>(&atile[arow * AT_LD + 32 + q * 8]);
#pragma unroll
    for (int jt = 0; jt < 8; jt++) {
        int j = jt * 16 + m;
        bf16x8v bf0 = *reinterpret_cast<const bf16x8v*>(&w1s[j * W1_LD + q * 8]);
        bf16x8v bf1 = *reinterpret_cast<const bf16x8v*>(&w1s[j * W1_LD + 32 + q * 8]);
        f32x4 acc = {0.f, 0.f, 0.f, 0.f};
        acc = __builtin_amdgcn_mfma_f32_16x16x32_bf16(a0, bf0, acc, 0, 0, 0);
        acc = __builtin_amdgcn_mfma_f32_16x16x32_bf16(a1, bf1, acc, 0, 0, 0);
        float bv = b1v[j];
#pragma unroll
        for (int r = 0; r < 4; r++) {
            float hv = fmaxf(acc[r] + bv, 0.f);
            htile[(hrow0 + r) * HT_LD + j] = f2bf(hv);
        }
    }

    // GEMM2: OUT = relu(H) @ W2 (wave-private rows; lgkmcnt orders ds ops)
    bf16x8v ha0 = *reinterpret_cast<const bf16x8v*>(&htile[arow * HT_LD + 0 * 32 + q * 8]);
    bf16x8v ha1 = *reinterpret_cast<const bf16x8v*>(&htile[arow * HT_LD + 1 * 32 + q * 8]);
    bf16x8v ha2 = *reinterpret_cast<const bf16x8v*>(&htile[arow * HT_LD + 2 * 32 + q * 8]);
    bf16x8v ha3 = *reinterpret_cast<const bf16x8v*>(&htile[arow * HT_LD + 3 * 32 + q * 8]);
#pragma unroll
    for (int dt = 0; dt < 4; dt++) {
        int d = dt * 16 + m;
        f32x4 acc = {0.f, 0.f, 0.f, 0.f};
        bf16x8v bw0 = *reinterpret_cast<const bf16x8v*>(&w2s[d * W2_LD + 0 * 32 + q * 8]);
        bf16x8v bw1 = *reinterpret_cast<const bf16x8v*>(&w2s[d * W2_LD + 1 * 32 + q * 8]);
        bf16x8v bw2 = *reinterpret_cast<const bf16x8v*>(&w2s[d * W2_LD + 2 * 32 + q * 8]);
        bf16x8v bw3 = *reinterpret_cast<const bf16x8v*>(&w2s[d * W2_LD + 3 * 32 + q * 8]);
        acc = __builtin_amdgcn_mfma_f32_16x16x32_bf16(ha0, bw0, acc, 0, 0, 0);
        acc = __builtin_amdgcn_mfma_f32_16x16x32_bf16(ha1, bw1, acc, 0, 0, 0);
        acc = __builtin_amdgcn_mfma_f32_16x16x32_bf16(ha2, bw2, acc, 0, 0, 0);
        acc = __builtin_amdgcn_mfma_f32_16x16x32_bf16(ha3, bw3, acc, 0, 0, 0);
        float bv = b2v[d];
#pragma unroll
        for (int r = 0; r < 4; r++) {
            int node = nb + hrow0 + r;
            if (node < N_NODES) out[(size_t)node * D_INF + d] = acc[r] + bv;
        }
    }
}

// ---------------------------------------------------------------------------
// Fallback (atomic scatter + convert) — used only if ws_size is too small
// ---------------------------------------------------------------------------

__global__ void init_agg_kernel(const float* __restrict__ x, float* __restrict__ agg) {
    int i = blockIdx.x * blockDim.x + threadIdx.x;
    int n4 = N_NODES * D_INF / 4;
    if (i < n4) {
        reinterpret_cast<float4*>(agg)[i] = reinterpret_cast<const float4*>(x)[i];
    }
}

__global__ void scatter_kernel(const float* __restrict__ x,
                               const int* __restrict__ src,
                               const int* __restrict__ dst,
                               float* __restrict__ agg) {
    int tid = blockIdx.x * blockDim.x + threadIdx.x;
    int e = tid >> 6;
    int d = tid & 63;
    if (e < N_EDGES) {
        atomicAdd(&agg[(size_t)dst[e] * D_INF + d], x[(size_t)src[e] * D_INF + d]);
    }
}

__global__ void cvt_agg_kernel(const float* __restrict__ agg32, ushort* __restrict__ aggb) {
    int i = blockIdx.x * blockDim.x + threadIdx.x;
    if (i < N_NODES * D_INF) aggb[i] = f2bf(agg32[i]);
}

// ---------------------------------------------------------------------------

extern "C" void kernel_launch(void* const* d_in, const int* in_sizes, int n_in,
                              void* d_out, int out_size, void* d_ws, size_t ws_size,
                              hipStream_t stream) {
    const float* x   = (const float*)d_in[0];
    const int* edge  = (const int*)d_in[1];   // [2, E]: src = edge, dst = edge + E
    const float* W1  = (const float*)d_in[2];
    const float* b1  = (const float*)d_in[3];
    const float* W2  = (const float*)d_in[4];
    const float* b2  = (const float*)d_in[5];
    float* out       = (float*)d_out;

    const int* src = edge;
    const int* dst = edge + N_EDGES;

    // Workspace layout:
    //   aggb  : N*64 bf16   (6.4 MB)
    //   w1tb  : 128*64 bf16 (16 KB)   w2tb: 64*128 bf16 (16 KB)
    //   head  : NCHAIN*N ints (800 KB)
    //   next  : E ints (3.2 MB)
    //   (fallback only, overlapping head/next region): agg32 N*64 floats
    ushort* aggb = (ushort*)d_ws;
    ushort* w1tb = aggb + (size_t)N_NODES * D_INF;
    ushort* w2tb = w1tb + D_INF * D_HIDF;
    int* head    = (int*)(w2tb + D_INF * D_HIDF);
    int* next    = head + NCHAIN * N_NODES;
    float* agg32 = (float*)(((uintptr_t)head + 15) & ~(uintptr_t)15);

    size_t needed_chain = (uintptr_t)(next + N_EDGES) - (uintptr_t)d_ws;
    size_t needed_fb    = ((uintptr_t)agg32 + (size_t)N_NODES * D_INF * 4) - (uintptr_t)d_ws;

    prep_weights_kernel<<<(D_INF * D_HIDF + 255) / 256, 256, 0, stream>>>(W1, W2, w1tb, w2tb);

    if (ws_size >= needed_chain) {
        init_head_kernel<<<(NCHAIN * N_NODES + 255) / 256, 256, 0, stream>>>(head);
        build_chain_kernel<<<(N_EDGES + 255) / 256, 256, 0, stream>>>(dst, head, next);
        int threads = N_NODES * 64;
        gather_chain_kernel<<<(threads + 255) / 256, 256, 0, stream>>>(x, src, head, next, aggb);
    } else if (ws_size >= needed_fb) {
        int n4 = N_NODES * D_INF / 4;
        init_agg_kernel<<<(n4 + 255) / 256, 256, 0, stream>>>(x, agg32);
        int work = N_EDGES * D_INF;
        scatter_kernel<<<(work + 255) / 256, 256, 0, stream>>>(x, src, dst, agg32);
        cvt_agg_kernel<<<(N_NODES * D_INF + 255) / 256, 256, 0, stream>>>(agg32, aggb);
    }

    // MLP: 64-node tiles, 4 waves/block, bf16 MFMA
    mlp_mfma_kernel<<<(N_NODES + 63) / 64, 256, 0, stream>>>(aggb, w1tb, b1, w2tb, b2, out);
}